// Round 1
// baseline (1889.908 us; speedup 1.0000x reference)
//
#include <hip/hip_runtime.h>

// Shapes (fixed by the problem)
#define NB 8
#define NC 512
#define ND 256
#define NP 4096
#define NHD 8
#define TWO_PI 6.2831853071795864f
#define FPITCH 65

__device__ __forceinline__ float2 cmulf(float2 a, float2 b) {
    return make_float2(a.x*b.x - a.y*b.y, a.x*b.y + a.y*b.x);
}
__device__ __forceinline__ float2 caddf(float2 a, float2 b) { return make_float2(a.x+b.x, a.y+b.y); }
__device__ __forceinline__ float2 csubf(float2 a, float2 b) { return make_float2(a.x-b.x, a.y-b.y); }

// 8-point DFT in registers. S=-1 forward, S=+1 inverse (unscaled).
template<int S>
__device__ __forceinline__ void dft8(float2 v[8]) {
    float2 e0=v[0], e1=v[2], e2=v[4], e3=v[6];
    float2 o0=v[1], o1=v[3], o2=v[5], o3=v[7];
    float2 p0=caddf(e0,e2), p1=csubf(e0,e2), q0=caddf(e1,e3), q1=csubf(e1,e3);
    float2 q1r = make_float2(-(float)S*q1.y, (float)S*q1.x);
    float2 E0=caddf(p0,q0), E2=csubf(p0,q0), E1=caddf(p1,q1r), E3=csubf(p1,q1r);
    p0=caddf(o0,o2); p1=csubf(o0,o2); q0=caddf(o1,o3); q1=csubf(o1,o3);
    q1r = make_float2(-(float)S*q1.y, (float)S*q1.x);
    float2 O0=caddf(p0,q0), O2=csubf(p0,q0), O1=caddf(p1,q1r), O3=csubf(p1,q1r);
    const float r = 0.70710678118654752f;
    float2 w1 = make_float2(r, (float)S*r);
    float2 w2 = make_float2(0.f, (float)S);
    float2 w3 = make_float2(-r, (float)S*r);
    float2 t;
    t = O0;           v[0]=caddf(E0,t); v[4]=csubf(E0,t);
    t = cmulf(w1,O1); v[1]=caddf(E1,t); v[5]=csubf(E1,t);
    t = cmulf(w2,O2); v[2]=caddf(E2,t); v[6]=csubf(E2,t);
    t = cmulf(w3,O3); v[3]=caddf(E3,t); v[7]=csubf(E3,t);
}

// 64-pt transform along the contiguous axis of each of 64 rows in LDS planes.
// Thread layout: r = (tid&31)+32*half, sub-index t8 = tid>>5.
// MODE 0: in-place.  MODE 1: write complex gout[r + 64*k] * scale (transposed, used by 4096-IFFT step C).
template<int S, int MODE>
__device__ void fft64_rows(float* Re, float* Im, const float* twc, const float* tws,
                           int tid, float2* gout, float scale)
{
    int rb = tid & 31;
    int t8 = tid >> 5;
    for (int half = 0; half < 2; ++half) {
        int r = rb + 32*half;
        float2 v[8];
        __syncthreads();
        #pragma unroll
        for (int m = 0; m < 8; ++m) {
            int idx = r*FPITCH + 8*m + t8;
            v[m] = make_float2(Re[idx], Im[idx]);
        }
        dft8<S>(v);
        #pragma unroll
        for (int k1 = 1; k1 < 8; ++k1) {
            int mm = (t8*k1) & 63;
            v[k1] = cmulf(v[k1], make_float2(twc[mm], (float)S*tws[mm]));
        }
        __syncthreads();
        #pragma unroll
        for (int k1 = 0; k1 < 8; ++k1) {
            int idx = r*FPITCH + k1*8 + t8;
            Re[idx] = v[k1].x; Im[idx] = v[k1].y;
        }
        __syncthreads();
        float2 a[8];
        #pragma unroll
        for (int m = 0; m < 8; ++m) {
            int idx = r*FPITCH + t8*8 + m;
            a[m] = make_float2(Re[idx], Im[idx]);
        }
        dft8<S>(a);
        if (MODE == 0) {
            __syncthreads();
            #pragma unroll
            for (int k2 = 0; k2 < 8; ++k2) {
                int idx = r*FPITCH + t8 + 8*k2;
                Re[idx] = a[k2].x; Im[idx] = a[k2].y;
            }
        } else {
            #pragma unroll
            for (int k2 = 0; k2 < 8; ++k2) {
                int kq = t8 + 8*k2;
                gout[r + 64*kq] = make_float2(a[k2].x*scale, a[k2].y*scale);
            }
        }
    }
    __syncthreads();
}

// 64-pt transform along the vertical axis of each of 64 columns.
// MODE 0: in-place. MODE 1: in-place * e^{S*2pi*i*row*col/4096} (mid twiddle of 4096-IFFT step A).
// MODE 2: write complex gout[row*64+col]*scale. MODE 3: write scale*|.| to goutr[row*64+col].
template<int S, int MODE>
__device__ void fft64_cols(float* Re, float* Im, const float* twc, const float* tws,
                           int tid, float2* gout, float* goutr, float scale)
{
    int cb = tid & 31;
    int t8 = tid >> 5;
    for (int half = 0; half < 2; ++half) {
        int col = cb + 32*half;
        float2 v[8];
        __syncthreads();
        #pragma unroll
        for (int m = 0; m < 8; ++m) {
            int idx = (8*m + t8)*FPITCH + col;
            v[m] = make_float2(Re[idx], Im[idx]);
        }
        dft8<S>(v);
        #pragma unroll
        for (int k1 = 1; k1 < 8; ++k1) {
            int mm = (t8*k1) & 63;
            v[k1] = cmulf(v[k1], make_float2(twc[mm], (float)S*tws[mm]));
        }
        __syncthreads();
        #pragma unroll
        for (int k1 = 0; k1 < 8; ++k1) {
            int idx = (k1*8 + t8)*FPITCH + col;
            Re[idx] = v[k1].x; Im[idx] = v[k1].y;
        }
        __syncthreads();
        float2 a[8];
        #pragma unroll
        for (int m = 0; m < 8; ++m) {
            int idx = (t8*8 + m)*FPITCH + col;
            a[m] = make_float2(Re[idx], Im[idx]);
        }
        dft8<S>(a);
        if (MODE <= 1) {
            __syncthreads();
            #pragma unroll
            for (int k2 = 0; k2 < 8; ++k2) {
                int row = t8 + 8*k2;
                float2 rv = a[k2];
                if (MODE == 1) {
                    float sv, cv;
                    __sincosf((TWO_PI/4096.f) * (float)(row*col), &sv, &cv);
                    rv = cmulf(rv, make_float2(cv, (float)S*sv));
                }
                int idx = row*FPITCH + col;
                Re[idx] = rv.x; Im[idx] = rv.y;
            }
        } else if (MODE == 2) {
            #pragma unroll
            for (int k2 = 0; k2 < 8; ++k2) {
                int row = t8 + 8*k2;
                gout[row*64 + col] = make_float2(a[k2].x*scale, a[k2].y*scale);
            }
        } else {
            #pragma unroll
            for (int k2 = 0; k2 < 8; ++k2) {
                int row = t8 + 8*k2;
                goutr[row*64 + col] = scale * sqrtf(a[k2].x*a[k2].x + a[k2].y*a[k2].y);
            }
        }
    }
    __syncthreads();
}

#define FMA16() do { \
    float a0=Xs[k][ty*4+0], a1=Xs[k][ty*4+1], a2=Xs[k][ty*4+2], a3=Xs[k][ty*4+3]; \
    float w0=Ws[k][tx*4+0], w1_=Ws[k][tx*4+1], w2_=Ws[k][tx*4+2], w3_=Ws[k][tx*4+3]; \
    acc[0][0]+=a0*w0; acc[0][1]+=a0*w1_; acc[0][2]+=a0*w2_; acc[0][3]+=a0*w3_; \
    acc[1][0]+=a1*w0; acc[1][1]+=a1*w1_; acc[1][2]+=a1*w2_; acc[1][3]+=a1*w3_; \
    acc[2][0]+=a2*w0; acc[2][1]+=a2*w1_; acc[2][2]+=a2*w2_; acc[2][3]+=a2*w3_; \
    acc[3][0]+=a3*w0; acc[3][1]+=a3*w1_; acc[3][2]+=a3*w2_; acc[3][3]+=a3*w3_; \
} while (0)

// conv weights (256,512,3,3) -> wT[t][i][o] for coalesced o-reads
__global__ __launch_bounds__(256) void k_wtrans(const float* __restrict__ w, float* __restrict__ wT) {
    int idx = blockIdx.x*256 + threadIdx.x;
    if (idx >= 9*NC*ND) return;
    int o = idx & 255;
    int rest = idx >> 8;
    int i = rest & 511;
    int t = rest >> 9;
    wT[idx] = w[(o*NC + i)*9 + t];
}

// dilated 3x3 conv (d=3, pad=3) + bias + BN + ReLU.  out[b][o][p], tile 64 px (one h-row) x 64 oc.
__global__ __launch_bounds__(256) void k_conv(const float* __restrict__ x, const float* __restrict__ wT,
        const float* __restrict__ cb, const float* __restrict__ bg, const float* __restrict__ bb,
        const float* __restrict__ bm, const float* __restrict__ bv, float* __restrict__ out)
{
    __shared__ float Xs[16][64];
    __shared__ float Ws[16][64];
    int tid = threadIdx.x;
    int hrow = blockIdx.x;
    int o0 = blockIdx.y * 64;
    int b = blockIdx.z;
    int tx = tid & 15, ty = tid >> 4;
    float acc[4][4] = {{0.f}};
    const float* xb = x + (size_t)b*NP*NC;
    int ldp = tid & 63, ldk = (tid >> 6) * 4;   // Xs loader: 1 pixel, 4 consecutive c
    int lwk = tid >> 4, lwo = (tid & 15) * 4;   // Ws loader: 1 k, 4 consecutive o
    for (int t = 0; t < 9; ++t) {
        int dh = (t/3)*3 - 3, dw = (t%3)*3 - 3;
        int h2 = hrow + dh;
        int w2 = ldp + dw;
        bool ok = (((unsigned)h2) < 64u) && (((unsigned)w2) < 64u);
        const float* xsrc = xb + (long long)(h2*64 + w2)*NC;
        for (int kc = 0; kc < NC; kc += 16) {
            float4 xv = make_float4(0.f,0.f,0.f,0.f);
            if (ok) xv = *(const float4*)(xsrc + kc + ldk);
            float4 wv = *(const float4*)(wT + ((size_t)t*NC + kc + lwk)*ND + o0 + lwo);
            __syncthreads();
            Xs[ldk+0][ldp]=xv.x; Xs[ldk+1][ldp]=xv.y; Xs[ldk+2][ldp]=xv.z; Xs[ldk+3][ldp]=xv.w;
            Ws[lwk][lwo+0]=wv.x; Ws[lwk][lwo+1]=wv.y; Ws[lwk][lwo+2]=wv.z; Ws[lwk][lwo+3]=wv.w;
            __syncthreads();
            #pragma unroll
            for (int k = 0; k < 16; ++k) { FMA16(); }
        }
    }
    #pragma unroll
    for (int oi = 0; oi < 4; ++oi) {
        int o = o0 + tx*4 + oi;
        float inv = bg[o] * rsqrtf(bv[o] + 1e-5f);
        float beta = bb[o] - bm[o]*inv;
        float cbo = cb[o];
        float4 rv;
        rv.x = fmaxf((acc[0][oi] + cbo)*inv + beta, 0.f);
        rv.y = fmaxf((acc[1][oi] + cbo)*inv + beta, 0.f);
        rv.z = fmaxf((acc[2][oi] + cbo)*inv + beta, 0.f);
        rv.w = fmaxf((acc[3][oi] + cbo)*inv + beta, 0.f);
        *(float4*)(out + ((size_t)(b*ND + o))*NP + hrow*64 + ty*4) = rv;
    }
}

// fft2 (forward) of one 64x64 real image -> complex F[kh*64+kw]
__global__ __launch_bounds__(256) void k_fft2_fwd(const float* __restrict__ src, float2* __restrict__ F) {
    __shared__ float Re[64*FPITCH];
    __shared__ float Im[64*FPITCH];
    __shared__ float twc[64], tws[64];
    int tid = threadIdx.x;
    size_t img = blockIdx.x;
    const float* s = src + img*4096;
    if (tid < 64) { float sv, cv; __sincosf(TWO_PI*(float)tid/64.f, &sv, &cv); twc[tid]=cv; tws[tid]=sv; }
    for (int i = tid; i < 4096; i += 256) {
        Re[(i>>6)*FPITCH + (i&63)] = s[i];
        Im[(i>>6)*FPITCH + (i&63)] = 0.f;
    }
    fft64_rows<-1,0>(Re, Im, twc, tws, tid, nullptr, 1.f);
    fft64_cols<-1,2>(Re, Im, twc, tws, tid, F + img*4096, nullptr, 1.f);
}

// 4096-pt inverse FFT of one f-row (Cooley-Tukey 64x64): Z[k1+64*k2], includes 1/4096
__global__ __launch_bounds__(256) void k_ifft_row4096(const float2* __restrict__ f, float2* __restrict__ Z) {
    __shared__ float Re[64*FPITCH];
    __shared__ float Im[64*FPITCH];
    __shared__ float twc[64], tws[64];
    int tid = threadIdx.x;
    size_t img = blockIdx.x;
    const float2* s = f + img*4096;
    if (tid < 64) { float sv, cv; __sincosf(TWO_PI*(float)tid/64.f, &sv, &cv); twc[tid]=cv; tws[tid]=sv; }
    for (int i = tid; i < 4096; i += 256) {
        float2 v = s[i];
        Re[(i>>6)*FPITCH + (i&63)] = v.x;
        Im[(i>>6)*FPITCH + (i&63)] = v.y;
    }
    fft64_cols<1,1>(Re, Im, twc, tws, tid, nullptr, nullptr, 1.f);       // along n1 + mid twiddle
    fft64_rows<1,1>(Re, Im, twc, tws, tid, Z + img*4096, 1.f/4096.f);    // along n2 -> global
}

// ifft2 of one 64x64 complex image, abs, * 1/4096
__global__ __launch_bounds__(256) void k_ifft2_abs(const float2* __restrict__ gf, float* __restrict__ out) {
    __shared__ float Re[64*FPITCH];
    __shared__ float Im[64*FPITCH];
    __shared__ float twc[64], tws[64];
    int tid = threadIdx.x;
    size_t img = blockIdx.x;
    const float2* s = gf + img*4096;
    if (tid < 64) { float sv, cv; __sincosf(TWO_PI*(float)tid/64.f, &sv, &cv); twc[tid]=cv; tws[tid]=sv; }
    for (int i = tid; i < 4096; i += 256) {
        float2 v = s[i];
        Re[(i>>6)*FPITCH + (i&63)] = v.x;
        Im[(i>>6)*FPITCH + (i&63)] = v.y;
    }
    fft64_rows<1,0>(Re, Im, twc, tws, tid, nullptr, 1.f);
    fft64_cols<1,3>(Re, Im, twc, tws, tid, nullptr, out + img*4096, 1.f/4096.f);
}

// per-(b,ch) L2 norm of f row
__global__ __launch_bounds__(256) void k_norm(const float2* __restrict__ f, float* __restrict__ nrm) {
    size_t img = blockIdx.x;
    int tid = threadIdx.x;
    const float2* s = f + img*4096;
    float acc = 0.f;
    for (int i = tid; i < 4096; i += 256) { float2 v = s[i]; acc += v.x*v.x + v.y*v.y; }
    #pragma unroll
    for (int off = 32; off > 0; off >>= 1) acc += __shfl_down(acc, off, 64);
    __shared__ float part[4];
    if ((tid & 63) == 0) part[tid >> 6] = acc;
    __syncthreads();
    if (tid == 0) nrm[img] = fmaxf(sqrtf(part[0]+part[1]+part[2]+part[3]), 1e-12f);
}

// G[c][d] = sum_n f_c[n]*f_d[n] (complex, no conj), split over n into 8 partials
__global__ __launch_bounds__(256) void k_gram(const float2* __restrict__ f, float2* __restrict__ Gpart) {
    int split = blockIdx.x;
    int bh = blockIdx.y;
    int b = bh >> 3, h = bh & 7;
    int tid = threadIdx.x;
    int ci = tid >> 3, dg = tid & 7;
    __shared__ float2 ft[32][65];
    const float2* fb = f + ((size_t)(b*ND + h*32))*NP;
    float2 acc[4];
    acc[0]=acc[1]=acc[2]=acc[3]=make_float2(0.f,0.f);
    for (int chunk = 0; chunk < 8; ++chunk) {
        int nbase = split*512 + chunk*64;
        __syncthreads();
        for (int i = tid; i < 2048; i += 256)
            ft[i>>6][i&63] = fb[(size_t)(i>>6)*NP + nbase + (i&63)];
        __syncthreads();
        for (int nn = 0; nn < 64; ++nn) {
            float2 fc = ft[ci][nn];
            #pragma unroll
            for (int j = 0; j < 4; ++j) {
                float2 fd = ft[dg*4+j][nn];
                acc[j].x += fc.x*fd.x - fc.y*fd.y;
                acc[j].y += fc.x*fd.y + fc.y*fd.x;
            }
        }
    }
    float2* g = Gpart + ((size_t)bh*8 + split)*1024;
    #pragma unroll
    for (int j = 0; j < 4; ++j) g[ci*32 + dg*4 + j] = acc[j];
}

// reduce partials, normalize, *temp, dual softmax, then A' = (1/32) W32+ @ S
__global__ __launch_bounds__(256) void k_attn(const float2* __restrict__ Gpart, const float* __restrict__ nrm,
                                              const float* __restrict__ temp, float2* __restrict__ Ap) {
    int bh = blockIdx.x;
    int b = bh >> 3, h = bh & 7;
    int tid = threadIdx.x;
    __shared__ float2 Sm[32][33];
    __shared__ float twc[32], tws[32];
    if (tid < 32) { float sv, cv; __sincosf(TWO_PI*(float)tid/32.f, &sv, &cv); twc[tid]=cv; tws[tid]=sv; }
    const float* nb = nrm + b*ND + h*32;
    float tv = temp[h];
    const float2* gp = Gpart + (size_t)bh*8*1024;
    #pragma unroll
    for (int j = 0; j < 4; ++j) {
        int e = tid*4 + j;
        int c = e >> 5, d = e & 31;
        float2 s = make_float2(0.f, 0.f);
        for (int sp = 0; sp < 8; ++sp) { float2 v = gp[sp*1024 + e]; s.x += v.x; s.y += v.y; }
        float sc = tv / (nb[c]*nb[d]);
        Sm[c][d] = make_float2(s.x*sc, s.y*sc);
    }
    __syncthreads();
    if (tid < 32) {
        float mr = -1e30f, mi = -1e30f;
        for (int d = 0; d < 32; ++d) { float2 v = Sm[tid][d]; mr = fmaxf(mr, v.x); mi = fmaxf(mi, v.y); }
        float sr = 0.f, si = 0.f;
        for (int d = 0; d < 32; ++d) {
            float2 v = Sm[tid][d];
            v.x = __expf(v.x - mr); v.y = __expf(v.y - mi);
            sr += v.x; si += v.y;
            Sm[tid][d] = v;
        }
        float ir = 1.f/sr, ii = 1.f/si;
        for (int d = 0; d < 32; ++d) { float2 v = Sm[tid][d]; Sm[tid][d] = make_float2(v.x*ir, v.y*ii); }
    }
    __syncthreads();
    float2* ap = Ap + (size_t)bh*1024;
    #pragma unroll
    for (int j = 0; j < 4; ++j) {
        int e = tid*4 + j;
        int k = e >> 5, d = e & 31;
        float2 acc = make_float2(0.f, 0.f);
        for (int c = 0; c < 32; ++c) {
            int m = (c*k) & 31;
            float2 w = make_float2(twc[m], tws[m]);
            float2 v = Sm[c][d];
            acc.x += w.x*v.x - w.y*v.y;
            acc.y += w.x*v.y + w.y*v.x;
        }
        ap[e] = make_float2(acc.x*(1.f/32.f), acc.y*(1.f/32.f));
    }
}

// out_f2 = | A' @ Z |  per (b,head)
__global__ __launch_bounds__(256) void k_outf2(const float2* __restrict__ Ap, const float2* __restrict__ Z,
                                               float* __restrict__ outf2) {
    int nc = blockIdx.x, bh = blockIdx.y;
    int b = bh >> 3, h = bh & 7;
    int tid = threadIdx.x;
    __shared__ float2 A[32][32];
    const float2* ap = Ap + (size_t)bh*1024;
    for (int i = tid; i < 1024; i += 256) A[i>>5][i&31] = ap[i];
    __syncthreads();
    int n = nc*256 + tid;
    const float2* zb = Z + ((size_t)(b*ND + h*32))*NP + n;
    float2 z[32];
    #pragma unroll
    for (int d = 0; d < 32; ++d) z[d] = zb[(size_t)d*NP];
    float* ob = outf2 + ((size_t)(b*ND + h*32))*NP + n;
    for (int k = 0; k < 32; ++k) {
        float2 acc = make_float2(0.f, 0.f);
        #pragma unroll
        for (int d = 0; d < 32; ++d) {
            float2 a = A[k][d], zz = z[d];
            acc.x += a.x*zz.x - a.y*zz.y;
            acc.y += a.x*zz.y + a.y*zz.x;
        }
        ob[(size_t)k*NP] = sqrtf(acc.x*acc.x + acc.y*acc.y);
    }
}

// g1 = relu(BN(w1 @ Re(f)))
__global__ __launch_bounds__(256) void k_g1(const float2* __restrict__ f, const float* __restrict__ w1,
        const float* __restrict__ w1b, const float* __restrict__ gg, const float* __restrict__ gb,
        const float* __restrict__ gm, const float* __restrict__ gv, float* __restrict__ g1)
{
    int pc = blockIdx.x, b = blockIdx.y;
    int tid = threadIdx.x;
    __shared__ float w1s[16*256];
    for (int i = tid; i < 4096; i += 256) w1s[i] = w1[i];
    __syncthreads();
    int p = pc*256 + tid;
    const float2* fb = f + (size_t)b*ND*NP + p;
    float acc[16];
    #pragma unroll
    for (int j = 0; j < 16; ++j) acc[j] = 0.f;
    for (int i = 0; i < 256; ++i) {
        float v = fb[(size_t)i*NP].x;
        #pragma unroll
        for (int j = 0; j < 16; ++j) acc[j] += w1s[j*256 + i] * v;
    }
    float* go = g1 + (size_t)b*16*NP + p;
    #pragma unroll
    for (int j = 0; j < 16; ++j) {
        float inv = gg[j]*rsqrtf(gv[j] + 1e-5f);
        float val = (acc[j] + w1b[j])*inv + (gb[j] - gm[j]*inv);
        go[(size_t)j*NP] = fmaxf(val, 0.f);
    }
}

// gf = sigmoid(w2 @ g1 + b2) * f
__global__ __launch_bounds__(256) void k_gate(const float2* __restrict__ f, const float* __restrict__ g1,
        const float* __restrict__ w2, const float* __restrict__ w2b, float2* __restrict__ gf)
{
    int pc = blockIdx.x, ch = blockIdx.y, b = blockIdx.z;
    int tid = threadIdx.x;
    int p = pc*256 + tid;
    const float* g1b = g1 + (size_t)b*16*NP + p;
    float acc = w2b[ch];
    #pragma unroll
    for (int j = 0; j < 16; ++j) acc += w2[ch*16 + j] * g1b[(size_t)j*NP];
    float gate = 1.f / (1.f + __expf(-acc));
    size_t idx = ((size_t)(b*ND + ch))*NP + p;
    float2 v = f[idx];
    gf[idx] = make_float2(gate*v.x, gate*v.y);
}

// final: out[b][p][o] = proj_w @ (cat(out_f2,out_l2) + x2d) + proj_b, two K-sweeps for the two layouts
__global__ __launch_bounds__(256) void k_proj(const float* __restrict__ outf2, const float* __restrict__ outl2,
        const float* __restrict__ x, const float* __restrict__ pw, const float* __restrict__ pb,
        float* __restrict__ out)
{
    __shared__ float Xs[16][68];
    __shared__ float Ws[16][68];
    int tid = threadIdx.x;
    int p0 = blockIdx.x * 64;
    int o0 = blockIdx.y * 64;
    int b = blockIdx.z;
    int tx = tid & 15, ty = tid >> 4;
    float acc[4][4] = {{0.f}};
    const float* xb = x + (size_t)b*NP*NC;
    int lwo = tid >> 2, lwk = (tid & 3)*4;
    // part 1: concat channels, [c][p] layout
    {
        int ldp = tid & 63, ldk = (tid >> 6)*4;
        const float* c0 = outf2 + (size_t)b*ND*NP;
        const float* c1 = outl2 + (size_t)b*ND*NP;
        for (int kc = 0; kc < NC; kc += 16) {
            float xv[4];
            #pragma unroll
            for (int j = 0; j < 4; ++j) {
                int c = kc + ldk + j;
                const float* src = (c < ND) ? (c0 + (size_t)c*NP) : (c1 + (size_t)(c-ND)*NP);
                xv[j] = src[p0 + ldp];
            }
            float4 wv = *(const float4*)(pw + (size_t)(o0 + lwo)*NC + kc + lwk);
            __syncthreads();
            #pragma unroll
            for (int j = 0; j < 4; ++j) Xs[ldk+j][ldp] = xv[j];
            Ws[lwk+0][lwo]=wv.x; Ws[lwk+1][lwo]=wv.y; Ws[lwk+2][lwo]=wv.z; Ws[lwk+3][lwo]=wv.w;
            __syncthreads();
            #pragma unroll
            for (int k = 0; k < 16; ++k) { FMA16(); }
        }
    }
    // part 2: + x, [p][c] layout
    {
        int ldp2 = tid >> 2, ldk2 = (tid & 3)*4;
        for (int kc = 0; kc < NC; kc += 16) {
            float4 xv = *(const float4*)(xb + (size_t)(p0 + ldp2)*NC + kc + ldk2);
            float4 wv = *(const float4*)(pw + (size_t)(o0 + lwo)*NC + kc + lwk);
            __syncthreads();
            Xs[ldk2+0][ldp2]=xv.x; Xs[ldk2+1][ldp2]=xv.y; Xs[ldk2+2][ldp2]=xv.z; Xs[ldk2+3][ldp2]=xv.w;
            Ws[lwk+0][lwo]=wv.x; Ws[lwk+1][lwo]=wv.y; Ws[lwk+2][lwo]=wv.z; Ws[lwk+3][lwo]=wv.w;
            __syncthreads();
            #pragma unroll
            for (int k = 0; k < 16; ++k) { FMA16(); }
        }
    }
    #pragma unroll
    for (int pi = 0; pi < 4; ++pi) {
        int p = p0 + ty*4 + pi;
        float4 rv;
        rv.x = acc[pi][0] + pb[o0+tx*4+0];
        rv.y = acc[pi][1] + pb[o0+tx*4+1];
        rv.z = acc[pi][2] + pb[o0+tx*4+2];
        rv.w = acc[pi][3] + pb[o0+tx*4+3];
        *(float4*)(out + ((size_t)(b*NP + p))*NC + o0 + tx*4) = rv;
    }
}

extern "C" void kernel_launch(void* const* d_in, const int* in_sizes, int n_in,
                              void* d_out, int out_size, void* d_ws, size_t ws_size,
                              hipStream_t stream)
{
    const float* x      = (const float*)d_in[0];
    const float* conv_w = (const float*)d_in[1];
    const float* conv_b = (const float*)d_in[2];
    const float* bn2g   = (const float*)d_in[3];
    const float* bn2b   = (const float*)d_in[4];
    const float* bn2m   = (const float*)d_in[5];
    const float* bn2v   = (const float*)d_in[6];
    const float* temp   = (const float*)d_in[7];
    const float* w1w    = (const float*)d_in[8];
    const float* w1b    = (const float*)d_in[9];
    const float* bnwg   = (const float*)d_in[10];
    const float* bnwb   = (const float*)d_in[11];
    const float* bnwm   = (const float*)d_in[12];
    const float* bnwv   = (const float*)d_in[13];
    const float* w2w    = (const float*)d_in[14];
    const float* w2b    = (const float*)d_in[15];
    const float* projw  = (const float*)d_in[16];
    const float* projb  = (const float*)d_in[17];
    float* out = (float*)d_out;

    char* ws = (char*)d_ws;
    // Overlay region [0, 6,823,936): wT (4.72 MB, dead after k_conv), then nrm/Gpart/Ap/g1.
    float*  wT    = (float*)(ws);
    float*  nrm   = (float*)(ws);
    float2* Gpart = (float2*)(ws + 8192);
    float2* Ap    = (float2*)(ws + 8192 + 4194304);
    float*  g1    = (float*)(ws + 8192 + 4194304 + 524288);
    char* base = ws + 6823936;
    float*  conv  = (float*)(base);                          // 33,554,432 B; later out_f2
    float2* f     = (float2*)(base + 33554432);              // 67,108,864 B; later out_l2 (first half)
    float2* Z     = (float2*)(base + 33554432 + 67108864);   // 67,108,864 B; later gate*f
    float*  outf2 = conv;
    float*  outl2 = (float*)f;
    float2* gf    = Z;
    // total workspace used: 174,596,096 bytes

    k_wtrans<<<dim3(4608), 256, 0, stream>>>(conv_w, wT);
    k_conv<<<dim3(64, 4, 8), 256, 0, stream>>>(x, wT, conv_b, bn2g, bn2b, bn2m, bn2v, conv);
    k_fft2_fwd<<<dim3(2048), 256, 0, stream>>>(conv, f);
    k_norm<<<dim3(2048), 256, 0, stream>>>(f, nrm);
    k_gram<<<dim3(8, 64), 256, 0, stream>>>(f, Gpart);
    k_attn<<<dim3(64), 256, 0, stream>>>(Gpart, nrm, temp, Ap);
    k_ifft_row4096<<<dim3(2048), 256, 0, stream>>>(f, Z);
    k_outf2<<<dim3(16, 64), 256, 0, stream>>>(Ap, Z, outf2);
    k_g1<<<dim3(16, 8), 256, 0, stream>>>(f, w1w, w1b, bnwg, bnwb, bnwm, bnwv, g1);
    k_gate<<<dim3(16, 256, 8), 256, 0, stream>>>(f, g1, w2w, w2b, gf);
    k_ifft2_abs<<<dim3(2048), 256, 0, stream>>>(gf, outl2);
    k_proj<<<dim3(64, 8, 8), 256, 0, stream>>>(outf2, outl2, x, projw, projb, out);
}

// Round 2
// 968.283 us; speedup vs baseline: 1.9518x; 1.9518x over previous
//
#include <hip/hip_runtime.h>

// Shapes (fixed by the problem)
#define NB 8
#define NC 512
#define ND 256
#define NP 4096
#define NHD 8
#define TWO_PI 6.2831853071795864f
#define FPITCH 65
#define HPAD 70

typedef short bf16x8 __attribute__((ext_vector_type(8)));
typedef float f32x4 __attribute__((ext_vector_type(4)));

__device__ __forceinline__ unsigned short f2bf(float f) {
    unsigned u = __float_as_uint(f);
    u += 0x7FFFu + ((u >> 16) & 1u);
    return (unsigned short)(u >> 16);
}

__device__ __forceinline__ void load_lds16(const void* g, void* l) {
    __builtin_amdgcn_global_load_lds((const __attribute__((address_space(1))) unsigned int*)g,
                                     (__attribute__((address_space(3))) unsigned int*)l, 16, 0, 0);
}

__device__ __forceinline__ float2 cmulf(float2 a, float2 b) {
    return make_float2(a.x*b.x - a.y*b.y, a.x*b.y + a.y*b.x);
}
__device__ __forceinline__ float2 caddf(float2 a, float2 b) { return make_float2(a.x+b.x, a.y+b.y); }
__device__ __forceinline__ float2 csubf(float2 a, float2 b) { return make_float2(a.x-b.x, a.y-b.y); }

// 8-point DFT in registers. S=-1 forward, S=+1 inverse (unscaled).
template<int S>
__device__ __forceinline__ void dft8(float2 v[8]) {
    float2 e0=v[0], e1=v[2], e2=v[4], e3=v[6];
    float2 o0=v[1], o1=v[3], o2=v[5], o3=v[7];
    float2 p0=caddf(e0,e2), p1=csubf(e0,e2), q0=caddf(e1,e3), q1=csubf(e1,e3);
    float2 q1r = make_float2(-(float)S*q1.y, (float)S*q1.x);
    float2 E0=caddf(p0,q0), E2=csubf(p0,q0), E1=caddf(p1,q1r), E3=csubf(p1,q1r);
    p0=caddf(o0,o2); p1=csubf(o0,o2); q0=caddf(o1,o3); q1=csubf(o1,o3);
    q1r = make_float2(-(float)S*q1.y, (float)S*q1.x);
    float2 O0=caddf(p0,q0), O2=csubf(p0,q0), O1=caddf(p1,q1r), O3=csubf(p1,q1r);
    const float r = 0.70710678118654752f;
    float2 w1 = make_float2(r, (float)S*r);
    float2 w2 = make_float2(0.f, (float)S);
    float2 w3 = make_float2(-r, (float)S*r);
    float2 t;
    t = O0;           v[0]=caddf(E0,t); v[4]=csubf(E0,t);
    t = cmulf(w1,O1); v[1]=caddf(E1,t); v[5]=csubf(E1,t);
    t = cmulf(w2,O2); v[2]=caddf(E2,t); v[6]=csubf(E2,t);
    t = cmulf(w3,O3); v[3]=caddf(E3,t); v[7]=csubf(E3,t);
}

// 64-pt transform along the contiguous axis of each of 64 rows in LDS planes.
template<int S, int MODE>
__device__ void fft64_rows(float* Re, float* Im, const float* twc, const float* tws,
                           int tid, float2* gout, float scale)
{
    int rb = tid & 31;
    int t8 = tid >> 5;
    for (int half = 0; half < 2; ++half) {
        int r = rb + 32*half;
        float2 v[8];
        __syncthreads();
        #pragma unroll
        for (int m = 0; m < 8; ++m) {
            int idx = r*FPITCH + 8*m + t8;
            v[m] = make_float2(Re[idx], Im[idx]);
        }
        dft8<S>(v);
        #pragma unroll
        for (int k1 = 1; k1 < 8; ++k1) {
            int mm = (t8*k1) & 63;
            v[k1] = cmulf(v[k1], make_float2(twc[mm], (float)S*tws[mm]));
        }
        __syncthreads();
        #pragma unroll
        for (int k1 = 0; k1 < 8; ++k1) {
            int idx = r*FPITCH + k1*8 + t8;
            Re[idx] = v[k1].x; Im[idx] = v[k1].y;
        }
        __syncthreads();
        float2 a[8];
        #pragma unroll
        for (int m = 0; m < 8; ++m) {
            int idx = r*FPITCH + t8*8 + m;
            a[m] = make_float2(Re[idx], Im[idx]);
        }
        dft8<S>(a);
        if (MODE == 0) {
            __syncthreads();
            #pragma unroll
            for (int k2 = 0; k2 < 8; ++k2) {
                int idx = r*FPITCH + t8 + 8*k2;
                Re[idx] = a[k2].x; Im[idx] = a[k2].y;
            }
        } else {
            #pragma unroll
            for (int k2 = 0; k2 < 8; ++k2) {
                int kq = t8 + 8*k2;
                gout[r + 64*kq] = make_float2(a[k2].x*scale, a[k2].y*scale);
            }
        }
    }
    __syncthreads();
}

// 64-pt transform along the vertical axis of each of 64 columns.
template<int S, int MODE>
__device__ void fft64_cols(float* Re, float* Im, const float* twc, const float* tws,
                           int tid, float2* gout, float* goutr, float scale)
{
    int cb = tid & 31;
    int t8 = tid >> 5;
    for (int half = 0; half < 2; ++half) {
        int col = cb + 32*half;
        float2 v[8];
        __syncthreads();
        #pragma unroll
        for (int m = 0; m < 8; ++m) {
            int idx = (8*m + t8)*FPITCH + col;
            v[m] = make_float2(Re[idx], Im[idx]);
        }
        dft8<S>(v);
        #pragma unroll
        for (int k1 = 1; k1 < 8; ++k1) {
            int mm = (t8*k1) & 63;
            v[k1] = cmulf(v[k1], make_float2(twc[mm], (float)S*tws[mm]));
        }
        __syncthreads();
        #pragma unroll
        for (int k1 = 0; k1 < 8; ++k1) {
            int idx = (k1*8 + t8)*FPITCH + col;
            Re[idx] = v[k1].x; Im[idx] = v[k1].y;
        }
        __syncthreads();
        float2 a[8];
        #pragma unroll
        for (int m = 0; m < 8; ++m) {
            int idx = (t8*8 + m)*FPITCH + col;
            a[m] = make_float2(Re[idx], Im[idx]);
        }
        dft8<S>(a);
        if (MODE <= 1) {
            __syncthreads();
            #pragma unroll
            for (int k2 = 0; k2 < 8; ++k2) {
                int row = t8 + 8*k2;
                float2 rv = a[k2];
                if (MODE == 1) {
                    float sv, cv;
                    __sincosf((TWO_PI/4096.f) * (float)(row*col), &sv, &cv);
                    rv = cmulf(rv, make_float2(cv, (float)S*sv));
                }
                int idx = row*FPITCH + col;
                Re[idx] = rv.x; Im[idx] = rv.y;
            }
        } else if (MODE == 2) {
            #pragma unroll
            for (int k2 = 0; k2 < 8; ++k2) {
                int row = t8 + 8*k2;
                gout[row*64 + col] = make_float2(a[k2].x*scale, a[k2].y*scale);
            }
        } else {
            #pragma unroll
            for (int k2 = 0; k2 < 8; ++k2) {
                int row = t8 + 8*k2;
                goutr[row*64 + col] = scale * sqrtf(a[k2].x*a[k2].x + a[k2].y*a[k2].y);
            }
        }
    }
    __syncthreads();
}

#define FMA16() do { \
    float a0=Xs[k][ty*4+0], a1=Xs[k][ty*4+1], a2=Xs[k][ty*4+2], a3=Xs[k][ty*4+3]; \
    float w0=Ws[k][tx*4+0], w1_=Ws[k][tx*4+1], w2_=Ws[k][tx*4+2], w3_=Ws[k][tx*4+3]; \
    acc[0][0]+=a0*w0; acc[0][1]+=a0*w1_; acc[0][2]+=a0*w2_; acc[0][3]+=a0*w3_; \
    acc[1][0]+=a1*w0; acc[1][1]+=a1*w1_; acc[1][2]+=a1*w2_; acc[1][3]+=a1*w3_; \
    acc[2][0]+=a2*w0; acc[2][1]+=a2*w1_; acc[2][2]+=a2*w2_; acc[2][3]+=a2*w3_; \
    acc[3][0]+=a3*w0; acc[3][1]+=a3*w1_; acc[3][2]+=a3*w2_; acc[3][3]+=a3*w3_; \
} while (0)

// conv weights (256,512,3,3) fp32 -> wB[t][o][i] bf16 (i contiguous = K-contiguous B rows)
__global__ __launch_bounds__(256) void k_wconv(const float* __restrict__ w, unsigned short* __restrict__ wB) {
    int idx = blockIdx.x*256 + threadIdx.x;
    if (idx >= 9*NC*ND) return;
    int i = idx & 511;
    int rest = idx >> 9;
    int o = rest & 255;
    int t = rest >> 8;
    wB[idx] = f2bf(w[(o*NC + i)*9 + t]);
}

// x (b, 4096, 512) fp32 -> spatially padded bf16 xpad[b][hp][wp][c], hp/wp in [0,70)
__global__ __launch_bounds__(256) void k_xpad(const float* __restrict__ x, unsigned short* __restrict__ xpad) {
    int idx = blockIdx.x*256 + threadIdx.x;   // 8*70*70*64 threads, 8 ch each
    int c8 = idx & 63;
    int rest = idx >> 6;
    int wp = rest % HPAD;
    int rest2 = rest / HPAD;
    int hp = rest2 % HPAD;
    int b = rest2 / HPAD;
    int h = hp - 3, w = wp - 3;
    bf16x8 v = {0,0,0,0,0,0,0,0};
    if (((unsigned)h) < 64u && ((unsigned)w) < 64u) {
        const float* s = x + (((size_t)b*NP + h*64 + w)*NC + c8*8);
        float4 f0 = *(const float4*)(s);
        float4 f1 = *(const float4*)(s + 4);
        v[0]=(short)f2bf(f0.x); v[1]=(short)f2bf(f0.y); v[2]=(short)f2bf(f0.z); v[3]=(short)f2bf(f0.w);
        v[4]=(short)f2bf(f1.x); v[5]=(short)f2bf(f1.y); v[6]=(short)f2bf(f1.z); v[7]=(short)f2bf(f1.w);
    }
    *(bf16x8*)(xpad + ((size_t)(b*HPAD*HPAD) + hp*HPAD + wp)*NC + c8*8) = v;
}

// bf16 MFMA implicit-GEMM dilated conv (d=3,pad=3) + bias + BN + ReLU -> out[b][o][p] fp32
// 128x128 block tile, BK=32, global_load_lds(16B) staging, 4 waves x (4x4) 16x16x32 MFMAs.
__global__ __launch_bounds__(256, 2) void k_conv_mfma(
        const unsigned short* __restrict__ xpad, const unsigned short* __restrict__ wB,
        const float* __restrict__ cbias, const float* __restrict__ bg, const float* __restrict__ bb,
        const float* __restrict__ bm, const float* __restrict__ bv, float* __restrict__ out)
{
    __shared__ short Als[128*32];
    __shared__ short Bls[128*32];
    int tid = threadIdx.x;
    int p0 = blockIdx.x * 128;
    int o0 = blockIdx.y * 128;
    int b  = blockIdx.z;
    int lane = tid & 63;
    int wv = tid >> 6;
    int wr = wv >> 1, wc = wv & 1;
    int ln = lane & 15, kq = lane >> 4;

    f32x4 acc[4][4];
    #pragma unroll
    for (int i = 0; i < 4; ++i)
        #pragma unroll
        for (int j = 0; j < 4; ++j)
            acc[i][j] = (f32x4){0.f, 0.f, 0.f, 0.f};

    // loader: thread t covers rows (t>>2) and 64+(t>>2), 16B chunk (t&3)
    int r0 = tid >> 2;
    int c16 = tid & 3;
    int pA0 = p0 + r0, pA1 = p0 + 64 + r0;
    int h0 = pA0 >> 6, w0c = pA0 & 63;
    int h1 = pA1 >> 6, w1c = pA1 & 63;
    const unsigned short* xb = xpad + (size_t)b*(HPAD*HPAD)*NC;
    int oB0 = o0 + r0, oB1 = o0 + 64 + r0;
    short* AlsD0 = Als + tid*8;
    short* AlsD1 = Als + (256 + tid)*8;
    short* BlsD0 = Bls + tid*8;
    short* BlsD1 = Bls + (256 + tid)*8;

    for (int t = 0; t < 9; ++t) {
        int dh = (t/3)*3, dw = (t%3)*3;   // +3 pad offset folded in
        const unsigned short* ga0 = xb + ((size_t)((h0 + dh)*HPAD + (w0c + dw)))*NC + c16*8;
        const unsigned short* ga1 = xb + ((size_t)((h1 + dh)*HPAD + (w1c + dw)))*NC + c16*8;
        const unsigned short* gb0 = wB + ((size_t)(t*ND + oB0))*NC + c16*8;
        const unsigned short* gb1 = wB + ((size_t)(t*ND + oB1))*NC + c16*8;
        for (int kc = 0; kc < NC; kc += 32) {
            __syncthreads();
            load_lds16(ga0 + kc, AlsD0);
            load_lds16(ga1 + kc, AlsD1);
            load_lds16(gb0 + kc, BlsD0);
            load_lds16(gb1 + kc, BlsD1);
            __syncthreads();
            bf16x8 af[4], bfr[4];
            #pragma unroll
            for (int mi = 0; mi < 4; ++mi)
                af[mi] = *(const bf16x8*)&Als[(wr*64 + mi*16 + ln)*32 + kq*8];
            #pragma unroll
            for (int ni = 0; ni < 4; ++ni)
                bfr[ni] = *(const bf16x8*)&Bls[(wc*64 + ni*16 + ln)*32 + kq*8];
            #pragma unroll
            for (int mi = 0; mi < 4; ++mi)
                #pragma unroll
                for (int ni = 0; ni < 4; ++ni)
                    acc[mi][ni] = __builtin_amdgcn_mfma_f32_16x16x32_bf16(af[mi], bfr[ni], acc[mi][ni], 0, 0, 0);
        }
    }

    // epilogue: C/D layout col=lane&15 (o), row=kq*4+reg (p); regs are 4 consecutive p -> float4
    #pragma unroll
    for (int ni = 0; ni < 4; ++ni) {
        int o = o0 + wc*64 + ni*16 + ln;
        float inv = bg[o] * rsqrtf(bv[o] + 1e-5f);
        float beta = bb[o] - bm[o]*inv;
        float cbo = cbias[o];
        #pragma unroll
        for (int mi = 0; mi < 4; ++mi) {
            int p = p0 + wr*64 + mi*16 + kq*4;
            f32x4 v = acc[mi][ni];
            float4 rv;
            rv.x = fmaxf((v[0] + cbo)*inv + beta, 0.f);
            rv.y = fmaxf((v[1] + cbo)*inv + beta, 0.f);
            rv.z = fmaxf((v[2] + cbo)*inv + beta, 0.f);
            rv.w = fmaxf((v[3] + cbo)*inv + beta, 0.f);
            *(float4*)(out + ((size_t)(b*ND + o))*NP + p) = rv;
        }
    }
}

// fft2 (forward) of one 64x64 real image -> complex F[kh*64+kw]
__global__ __launch_bounds__(256) void k_fft2_fwd(const float* __restrict__ src, float2* __restrict__ F) {
    __shared__ float Re[64*FPITCH];
    __shared__ float Im[64*FPITCH];
    __shared__ float twc[64], tws[64];
    int tid = threadIdx.x;
    size_t img = blockIdx.x;
    const float* s = src + img*4096;
    if (tid < 64) { float sv, cv; __sincosf(TWO_PI*(float)tid/64.f, &sv, &cv); twc[tid]=cv; tws[tid]=sv; }
    for (int i = tid; i < 4096; i += 256) {
        Re[(i>>6)*FPITCH + (i&63)] = s[i];
        Im[(i>>6)*FPITCH + (i&63)] = 0.f;
    }
    fft64_rows<-1,0>(Re, Im, twc, tws, tid, nullptr, 1.f);
    fft64_cols<-1,2>(Re, Im, twc, tws, tid, F + img*4096, nullptr, 1.f);
}

// 4096-pt inverse FFT of one f-row (Cooley-Tukey 64x64): Z[k1+64*k2], includes 1/4096
__global__ __launch_bounds__(256) void k_ifft_row4096(const float2* __restrict__ f, float2* __restrict__ Z) {
    __shared__ float Re[64*FPITCH];
    __shared__ float Im[64*FPITCH];
    __shared__ float twc[64], tws[64];
    int tid = threadIdx.x;
    size_t img = blockIdx.x;
    const float2* s = f + img*4096;
    if (tid < 64) { float sv, cv; __sincosf(TWO_PI*(float)tid/64.f, &sv, &cv); twc[tid]=cv; tws[tid]=sv; }
    for (int i = tid; i < 4096; i += 256) {
        float2 v = s[i];
        Re[(i>>6)*FPITCH + (i&63)] = v.x;
        Im[(i>>6)*FPITCH + (i&63)] = v.y;
    }
    fft64_cols<1,1>(Re, Im, twc, tws, tid, nullptr, nullptr, 1.f);
    fft64_rows<1,1>(Re, Im, twc, tws, tid, Z + img*4096, 1.f/4096.f);
}

// ifft2 of one 64x64 complex image, abs, * 1/4096
__global__ __launch_bounds__(256) void k_ifft2_abs(const float2* __restrict__ gf, float* __restrict__ out) {
    __shared__ float Re[64*FPITCH];
    __shared__ float Im[64*FPITCH];
    __shared__ float twc[64], tws[64];
    int tid = threadIdx.x;
    size_t img = blockIdx.x;
    const float2* s = gf + img*4096;
    if (tid < 64) { float sv, cv; __sincosf(TWO_PI*(float)tid/64.f, &sv, &cv); twc[tid]=cv; tws[tid]=sv; }
    for (int i = tid; i < 4096; i += 256) {
        float2 v = s[i];
        Re[(i>>6)*FPITCH + (i&63)] = v.x;
        Im[(i>>6)*FPITCH + (i&63)] = v.y;
    }
    fft64_rows<1,0>(Re, Im, twc, tws, tid, nullptr, 1.f);
    fft64_cols<1,3>(Re, Im, twc, tws, tid, nullptr, out + img*4096, 1.f/4096.f);
}

// per-(b,ch) L2 norm of f row
__global__ __launch_bounds__(256) void k_norm(const float2* __restrict__ f, float* __restrict__ nrm) {
    size_t img = blockIdx.x;
    int tid = threadIdx.x;
    const float2* s = f + img*4096;
    float acc = 0.f;
    for (int i = tid; i < 4096; i += 256) { float2 v = s[i]; acc += v.x*v.x + v.y*v.y; }
    #pragma unroll
    for (int off = 32; off > 0; off >>= 1) acc += __shfl_down(acc, off, 64);
    __shared__ float part[4];
    if ((tid & 63) == 0) part[tid >> 6] = acc;
    __syncthreads();
    if (tid == 0) nrm[img] = fmaxf(sqrtf(part[0]+part[1]+part[2]+part[3]), 1e-12f);
}

// G[c][d] = sum_n f_c[n]*f_d[n] (complex, no conj), split over n into 8 partials
__global__ __launch_bounds__(256) void k_gram(const float2* __restrict__ f, float2* __restrict__ Gpart) {
    int split = blockIdx.x;
    int bh = blockIdx.y;
    int b = bh >> 3, h = bh & 7;
    int tid = threadIdx.x;
    int ci = tid >> 3, dg = tid & 7;
    __shared__ float2 ft[32][65];
    const float2* fb = f + ((size_t)(b*ND + h*32))*NP;
    float2 acc[4];
    acc[0]=acc[1]=acc[2]=acc[3]=make_float2(0.f,0.f);
    for (int chunk = 0; chunk < 8; ++chunk) {
        int nbase = split*512 + chunk*64;
        __syncthreads();
        for (int i = tid; i < 2048; i += 256)
            ft[i>>6][i&63] = fb[(size_t)(i>>6)*NP + nbase + (i&63)];
        __syncthreads();
        for (int nn = 0; nn < 64; ++nn) {
            float2 fc = ft[ci][nn];
            #pragma unroll
            for (int j = 0; j < 4; ++j) {
                float2 fd = ft[dg*4+j][nn];
                acc[j].x += fc.x*fd.x - fc.y*fd.y;
                acc[j].y += fc.x*fd.y + fc.y*fd.x;
            }
        }
    }
    float2* g = Gpart + ((size_t)bh*8 + split)*1024;
    #pragma unroll
    for (int j = 0; j < 4; ++j) g[ci*32 + dg*4 + j] = acc[j];
}

// reduce partials, normalize, *temp, dual softmax, then A' = (1/32) W32+ @ S
__global__ __launch_bounds__(256) void k_attn(const float2* __restrict__ Gpart, const float* __restrict__ nrm,
                                              const float* __restrict__ temp, float2* __restrict__ Ap) {
    int bh = blockIdx.x;
    int b = bh >> 3, h = bh & 7;
    int tid = threadIdx.x;
    __shared__ float2 Sm[32][33];
    __shared__ float twc[32], tws[32];
    if (tid < 32) { float sv, cv; __sincosf(TWO_PI*(float)tid/32.f, &sv, &cv); twc[tid]=cv; tws[tid]=sv; }
    const float* nb = nrm + b*ND + h*32;
    float tv = temp[h];
    const float2* gp = Gpart + (size_t)bh*8*1024;
    #pragma unroll
    for (int j = 0; j < 4; ++j) {
        int e = tid*4 + j;
        int c = e >> 5, d = e & 31;
        float2 s = make_float2(0.f, 0.f);
        for (int sp = 0; sp < 8; ++sp) { float2 v = gp[sp*1024 + e]; s.x += v.x; s.y += v.y; }
        float sc = tv / (nb[c]*nb[d]);
        Sm[c][d] = make_float2(s.x*sc, s.y*sc);
    }
    __syncthreads();
    if (tid < 32) {
        float mr = -1e30f, mi = -1e30f;
        for (int d = 0; d < 32; ++d) { float2 v = Sm[tid][d]; mr = fmaxf(mr, v.x); mi = fmaxf(mi, v.y); }
        float sr = 0.f, si = 0.f;
        for (int d = 0; d < 32; ++d) {
            float2 v = Sm[tid][d];
            v.x = __expf(v.x - mr); v.y = __expf(v.y - mi);
            sr += v.x; si += v.y;
            Sm[tid][d] = v;
        }
        float ir = 1.f/sr, ii = 1.f/si;
        for (int d = 0; d < 32; ++d) { float2 v = Sm[tid][d]; Sm[tid][d] = make_float2(v.x*ir, v.y*ii); }
    }
    __syncthreads();
    float2* ap = Ap + (size_t)bh*1024;
    #pragma unroll
    for (int j = 0; j < 4; ++j) {
        int e = tid*4 + j;
        int k = e >> 5, d = e & 31;
        float2 acc = make_float2(0.f, 0.f);
        for (int c = 0; c < 32; ++c) {
            int m = (c*k) & 31;
            float2 w = make_float2(twc[m], tws[m]);
            float2 v = Sm[c][d];
            acc.x += w.x*v.x - w.y*v.y;
            acc.y += w.x*v.y + w.y*v.x;
        }
        ap[e] = make_float2(acc.x*(1.f/32.f), acc.y*(1.f/32.f));
    }
}

// out_f2 = | A' @ Z |  per (b,head)
__global__ __launch_bounds__(256) void k_outf2(const float2* __restrict__ Ap, const float2* __restrict__ Z,
                                               float* __restrict__ outf2) {
    int nc = blockIdx.x, bh = blockIdx.y;
    int b = bh >> 3, h = bh & 7;
    int tid = threadIdx.x;
    __shared__ float2 A[32][32];
    const float2* ap = Ap + (size_t)bh*1024;
    for (int i = tid; i < 1024; i += 256) A[i>>5][i&31] = ap[i];
    __syncthreads();
    int n = nc*256 + tid;
    const float2* zb = Z + ((size_t)(b*ND + h*32))*NP + n;
    float2 z[32];
    #pragma unroll
    for (int d = 0; d < 32; ++d) z[d] = zb[(size_t)d*NP];
    float* ob = outf2 + ((size_t)(b*ND + h*32))*NP + n;
    for (int k = 0; k < 32; ++k) {
        float2 acc = make_float2(0.f, 0.f);
        #pragma unroll
        for (int d = 0; d < 32; ++d) {
            float2 a = A[k][d], zz = z[d];
            acc.x += a.x*zz.x - a.y*zz.y;
            acc.y += a.x*zz.y + a.y*zz.x;
        }
        ob[(size_t)k*NP] = sqrtf(acc.x*acc.x + acc.y*acc.y);
    }
}

// g1 = relu(BN(w1 @ Re(f)))
__global__ __launch_bounds__(256) void k_g1(const float2* __restrict__ f, const float* __restrict__ w1,
        const float* __restrict__ w1b, const float* __restrict__ gg, const float* __restrict__ gb,
        const float* __restrict__ gm, const float* __restrict__ gv, float* __restrict__ g1)
{
    int pc = blockIdx.x, b = blockIdx.y;
    int tid = threadIdx.x;
    __shared__ float w1s[16*256];
    for (int i = tid; i < 4096; i += 256) w1s[i] = w1[i];
    __syncthreads();
    int p = pc*256 + tid;
    const float2* fb = f + (size_t)b*ND*NP + p;
    float acc[16];
    #pragma unroll
    for (int j = 0; j < 16; ++j) acc[j] = 0.f;
    for (int i = 0; i < 256; ++i) {
        float v = fb[(size_t)i*NP].x;
        #pragma unroll
        for (int j = 0; j < 16; ++j) acc[j] += w1s[j*256 + i] * v;
    }
    float* go = g1 + (size_t)b*16*NP + p;
    #pragma unroll
    for (int j = 0; j < 16; ++j) {
        float inv = gg[j]*rsqrtf(gv[j] + 1e-5f);
        float val = (acc[j] + w1b[j])*inv + (gb[j] - gm[j]*inv);
        go[(size_t)j*NP] = fmaxf(val, 0.f);
    }
}

// gf = sigmoid(w2 @ g1 + b2) * f
__global__ __launch_bounds__(256) void k_gate(const float2* __restrict__ f, const float* __restrict__ g1,
        const float* __restrict__ w2, const float* __restrict__ w2b, float2* __restrict__ gf)
{
    int pc = blockIdx.x, ch = blockIdx.y, b = blockIdx.z;
    int tid = threadIdx.x;
    int p = pc*256 + tid;
    const float* g1b = g1 + (size_t)b*16*NP + p;
    float acc = w2b[ch];
    #pragma unroll
    for (int j = 0; j < 16; ++j) acc += w2[ch*16 + j] * g1b[(size_t)j*NP];
    float gate = 1.f / (1.f + __expf(-acc));
    size_t idx = ((size_t)(b*ND + ch))*NP + p;
    float2 v = f[idx];
    gf[idx] = make_float2(gate*v.x, gate*v.y);
}

// final: out[b][p][o] = proj_w @ (cat(out_f2,out_l2) + x2d) + proj_b, two K-sweeps for the two layouts
__global__ __launch_bounds__(256) void k_proj(const float* __restrict__ outf2, const float* __restrict__ outl2,
        const float* __restrict__ x, const float* __restrict__ pw, const float* __restrict__ pb,
        float* __restrict__ out)
{
    __shared__ float Xs[16][68];
    __shared__ float Ws[16][68];
    int tid = threadIdx.x;
    int p0 = blockIdx.x * 64;
    int o0 = blockIdx.y * 64;
    int b = blockIdx.z;
    int tx = tid & 15, ty = tid >> 4;
    float acc[4][4] = {{0.f}};
    const float* xb = x + (size_t)b*NP*NC;
    int lwo = tid >> 2, lwk = (tid & 3)*4;
    // part 1: concat channels, [c][p] layout
    {
        int ldp = tid & 63, ldk = (tid >> 6)*4;
        const float* c0 = outf2 + (size_t)b*ND*NP;
        const float* c1 = outl2 + (size_t)b*ND*NP;
        for (int kc = 0; kc < NC; kc += 16) {
            float xv[4];
            #pragma unroll
            for (int j = 0; j < 4; ++j) {
                int c = kc + ldk + j;
                const float* src = (c < ND) ? (c0 + (size_t)c*NP) : (c1 + (size_t)(c-ND)*NP);
                xv[j] = src[p0 + ldp];
            }
            float4 wv = *(const float4*)(pw + (size_t)(o0 + lwo)*NC + kc + lwk);
            __syncthreads();
            #pragma unroll
            for (int j = 0; j < 4; ++j) Xs[ldk+j][ldp] = xv[j];
            Ws[lwk+0][lwo]=wv.x; Ws[lwk+1][lwo]=wv.y; Ws[lwk+2][lwo]=wv.z; Ws[lwk+3][lwo]=wv.w;
            __syncthreads();
            #pragma unroll
            for (int k = 0; k < 16; ++k) { FMA16(); }
        }
    }
    // part 2: + x, [p][c] layout
    {
        int ldp2 = tid >> 2, ldk2 = (tid & 3)*4;
        for (int kc = 0; kc < NC; kc += 16) {
            float4 xv = *(const float4*)(xb + (size_t)(p0 + ldp2)*NC + kc + ldk2);
            float4 wv = *(const float4*)(pw + (size_t)(o0 + lwo)*NC + kc + lwk);
            __syncthreads();
            Xs[ldk2+0][ldp2]=xv.x; Xs[ldk2+1][ldp2]=xv.y; Xs[ldk2+2][ldp2]=xv.z; Xs[ldk2+3][ldp2]=xv.w;
            Ws[lwk+0][lwo]=wv.x; Ws[lwk+1][lwo]=wv.y; Ws[lwk+2][lwo]=wv.z; Ws[lwk+3][lwo]=wv.w;
            __syncthreads();
            #pragma unroll
            for (int k = 0; k < 16; ++k) { FMA16(); }
        }
    }
    #pragma unroll
    for (int pi = 0; pi < 4; ++pi) {
        int p = p0 + ty*4 + pi;
        float4 rv;
        rv.x = acc[pi][0] + pb[o0+tx*4+0];
        rv.y = acc[pi][1] + pb[o0+tx*4+1];
        rv.z = acc[pi][2] + pb[o0+tx*4+2];
        rv.w = acc[pi][3] + pb[o0+tx*4+3];
        *(float4*)(out + ((size_t)(b*NP + p))*NC + o0 + tx*4) = rv;
    }
}

extern "C" void kernel_launch(void* const* d_in, const int* in_sizes, int n_in,
                              void* d_out, int out_size, void* d_ws, size_t ws_size,
                              hipStream_t stream)
{
    const float* x      = (const float*)d_in[0];
    const float* conv_w = (const float*)d_in[1];
    const float* conv_b = (const float*)d_in[2];
    const float* bn2g   = (const float*)d_in[3];
    const float* bn2b   = (const float*)d_in[4];
    const float* bn2m   = (const float*)d_in[5];
    const float* bn2v   = (const float*)d_in[6];
    const float* temp   = (const float*)d_in[7];
    const float* w1w    = (const float*)d_in[8];
    const float* w1b    = (const float*)d_in[9];
    const float* bnwg   = (const float*)d_in[10];
    const float* bnwb   = (const float*)d_in[11];
    const float* bnwm   = (const float*)d_in[12];
    const float* bnwv   = (const float*)d_in[13];
    const float* w2w    = (const float*)d_in[14];
    const float* w2b    = (const float*)d_in[15];
    const float* projw  = (const float*)d_in[16];
    const float* projb  = (const float*)d_in[17];
    float* out = (float*)d_out;

    char* ws = (char*)d_ws;
    // Head overlay region [0, 6,823,936):
    //   wB bf16 (2,359,296 B) lives here during conv; nrm/Gpart/Ap/g1 reuse it afterwards.
    unsigned short* wB = (unsigned short*)(ws);
    float*  nrm   = (float*)(ws);
    float2* Gpart = (float2*)(ws + 8192);
    float2* Ap    = (float2*)(ws + 8192 + 4194304);
    float*  g1    = (float*)(ws + 8192 + 4194304 + 524288);
    char* base = ws + 6823936;
    float*  conv  = (float*)(base);                          // 33,554,432 B; later out_f2
    float2* f     = (float2*)(base + 33554432);              // 67,108,864 B; later out_l2
    float2* Z     = (float2*)(base + 33554432 + 67108864);   // 67,108,864 B; later gate*f
    // xpad bf16 (40,140,800 B) overlays the f region (dead until k_fft2_fwd)
    unsigned short* xpad = (unsigned short*)(base + 33554432);
    float*  outf2 = conv;
    float*  outl2 = (float*)f;
    float2* gf    = Z;
    // total workspace used: 174,596,096 bytes

    k_wconv<<<dim3(4608), 256, 0, stream>>>(conv_w, wB);
    k_xpad<<<dim3(9800), 256, 0, stream>>>(x, xpad);
    k_conv_mfma<<<dim3(32, 2, 8), 256, 0, stream>>>(xpad, wB, conv_b, bn2g, bn2b, bn2m, bn2v, conv);
    k_fft2_fwd<<<dim3(2048), 256, 0, stream>>>(conv, f);
    k_norm<<<dim3(2048), 256, 0, stream>>>(f, nrm);
    k_gram<<<dim3(8, 64), 256, 0, stream>>>(f, Gpart);
    k_attn<<<dim3(64), 256, 0, stream>>>(Gpart, nrm, temp, Ap);
    k_ifft_row4096<<<dim3(2048), 256, 0, stream>>>(f, Z);
    k_outf2<<<dim3(16, 64), 256, 0, stream>>>(Ap, Z, outf2);
    k_g1<<<dim3(16, 8), 256, 0, stream>>>(f, w1w, w1b, bnwg, bnwb, bnwm, bnwv, g1);
    k_gate<<<dim3(16, 256, 8), 256, 0, stream>>>(f, g1, w2w, w2b, gf);
    k_ifft2_abs<<<dim3(2048), 256, 0, stream>>>(gf, outl2);
    k_proj<<<dim3(64, 8, 8), 256, 0, stream>>>(outf2, outl2, x, projw, projb, out);
}

// Round 3
// 566.972 us; speedup vs baseline: 3.3333x; 1.7078x over previous
//
#include <hip/hip_runtime.h>

// Shapes (fixed by the problem)
#define NB 8
#define NC 512
#define ND 256
#define NP 4096
#define NHD 8
#define TWO_PI 6.2831853071795864f
#define FPITCH 65
#define HPAD 70

typedef short bf16x8 __attribute__((ext_vector_type(8)));
typedef float f32x4 __attribute__((ext_vector_type(4)));

__device__ __forceinline__ unsigned short f2bf(float f) {
    unsigned u = __float_as_uint(f);
    u += 0x7FFFu + ((u >> 16) & 1u);
    return (unsigned short)(u >> 16);
}
__device__ __forceinline__ float bf2f(unsigned short u) {
    return __uint_as_float((unsigned)u << 16);
}

__device__ __forceinline__ void load_lds16(const void* g, void* l) {
    __builtin_amdgcn_global_load_lds((const __attribute__((address_space(1))) unsigned int*)g,
                                     (__attribute__((address_space(3))) unsigned int*)l, 16, 0, 0);
}

__device__ __forceinline__ float2 cmulf(float2 a, float2 b) {
    return make_float2(a.x*b.x - a.y*b.y, a.x*b.y + a.y*b.x);
}
__device__ __forceinline__ float2 caddf(float2 a, float2 b) { return make_float2(a.x+b.x, a.y+b.y); }
__device__ __forceinline__ float2 csubf(float2 a, float2 b) { return make_float2(a.x-b.x, a.y-b.y); }

// 8-point DFT in registers. S=-1 forward, S=+1 inverse (unscaled).
template<int S>
__device__ __forceinline__ void dft8(float2 v[8]) {
    float2 e0=v[0], e1=v[2], e2=v[4], e3=v[6];
    float2 o0=v[1], o1=v[3], o2=v[5], o3=v[7];
    float2 p0=caddf(e0,e2), p1=csubf(e0,e2), q0=caddf(e1,e3), q1=csubf(e1,e3);
    float2 q1r = make_float2(-(float)S*q1.y, (float)S*q1.x);
    float2 E0=caddf(p0,q0), E2=csubf(p0,q0), E1=caddf(p1,q1r), E3=csubf(p1,q1r);
    p0=caddf(o0,o2); p1=csubf(o0,o2); q0=caddf(o1,o3); q1=csubf(o1,o3);
    q1r = make_float2(-(float)S*q1.y, (float)S*q1.x);
    float2 O0=caddf(p0,q0), O2=csubf(p0,q0), O1=caddf(p1,q1r), O3=csubf(p1,q1r);
    const float r = 0.70710678118654752f;
    float2 w1 = make_float2(r, (float)S*r);
    float2 w2 = make_float2(0.f, (float)S);
    float2 w3 = make_float2(-r, (float)S*r);
    float2 t;
    t = O0;           v[0]=caddf(E0,t); v[4]=csubf(E0,t);
    t = cmulf(w1,O1); v[1]=caddf(E1,t); v[5]=csubf(E1,t);
    t = cmulf(w2,O2); v[2]=caddf(E2,t); v[6]=csubf(E2,t);
    t = cmulf(w3,O3); v[3]=caddf(E3,t); v[7]=csubf(E3,t);
}

// 64-pt transform along the contiguous axis of each of 64 rows in LDS planes.
template<int S, int MODE>
__device__ void fft64_rows(float* Re, float* Im, const float* twc, const float* tws,
                           int tid, float2* gout, float scale)
{
    int rb = tid & 31;
    int t8 = tid >> 5;
    for (int half = 0; half < 2; ++half) {
        int r = rb + 32*half;
        float2 v[8];
        __syncthreads();
        #pragma unroll
        for (int m = 0; m < 8; ++m) {
            int idx = r*FPITCH + 8*m + t8;
            v[m] = make_float2(Re[idx], Im[idx]);
        }
        dft8<S>(v);
        #pragma unroll
        for (int k1 = 1; k1 < 8; ++k1) {
            int mm = (t8*k1) & 63;
            v[k1] = cmulf(v[k1], make_float2(twc[mm], (float)S*tws[mm]));
        }
        __syncthreads();
        #pragma unroll
        for (int k1 = 0; k1 < 8; ++k1) {
            int idx = r*FPITCH + k1*8 + t8;
            Re[idx] = v[k1].x; Im[idx] = v[k1].y;
        }
        __syncthreads();
        float2 a[8];
        #pragma unroll
        for (int m = 0; m < 8; ++m) {
            int idx = r*FPITCH + t8*8 + m;
            a[m] = make_float2(Re[idx], Im[idx]);
        }
        dft8<S>(a);
        if (MODE == 0) {
            __syncthreads();
            #pragma unroll
            for (int k2 = 0; k2 < 8; ++k2) {
                int idx = r*FPITCH + t8 + 8*k2;
                Re[idx] = a[k2].x; Im[idx] = a[k2].y;
            }
        } else {
            #pragma unroll
            for (int k2 = 0; k2 < 8; ++k2) {
                int kq = t8 + 8*k2;
                gout[r + 64*kq] = make_float2(a[k2].x*scale, a[k2].y*scale);
            }
        }
    }
    __syncthreads();
}

// 64-pt transform along the vertical axis of each of 64 columns.
// MODE 0: in-place. MODE 1: in-place * mid-twiddle. MODE 2: complex out. MODE 3: bf16 |.|*scale out.
template<int S, int MODE>
__device__ void fft64_cols(float* Re, float* Im, const float* twc, const float* tws,
                           int tid, float2* gout, unsigned short* goutr, float scale)
{
    int cb = tid & 31;
    int t8 = tid >> 5;
    for (int half = 0; half < 2; ++half) {
        int col = cb + 32*half;
        float2 v[8];
        __syncthreads();
        #pragma unroll
        for (int m = 0; m < 8; ++m) {
            int idx = (8*m + t8)*FPITCH + col;
            v[m] = make_float2(Re[idx], Im[idx]);
        }
        dft8<S>(v);
        #pragma unroll
        for (int k1 = 1; k1 < 8; ++k1) {
            int mm = (t8*k1) & 63;
            v[k1] = cmulf(v[k1], make_float2(twc[mm], (float)S*tws[mm]));
        }
        __syncthreads();
        #pragma unroll
        for (int k1 = 0; k1 < 8; ++k1) {
            int idx = (k1*8 + t8)*FPITCH + col;
            Re[idx] = v[k1].x; Im[idx] = v[k1].y;
        }
        __syncthreads();
        float2 a[8];
        #pragma unroll
        for (int m = 0; m < 8; ++m) {
            int idx = (t8*8 + m)*FPITCH + col;
            a[m] = make_float2(Re[idx], Im[idx]);
        }
        dft8<S>(a);
        if (MODE <= 1) {
            __syncthreads();
            #pragma unroll
            for (int k2 = 0; k2 < 8; ++k2) {
                int row = t8 + 8*k2;
                float2 rv = a[k2];
                if (MODE == 1) {
                    float sv, cv;
                    __sincosf((TWO_PI/4096.f) * (float)(row*col), &sv, &cv);
                    rv = cmulf(rv, make_float2(cv, (float)S*sv));
                }
                int idx = row*FPITCH + col;
                Re[idx] = rv.x; Im[idx] = rv.y;
            }
        } else if (MODE == 2) {
            #pragma unroll
            for (int k2 = 0; k2 < 8; ++k2) {
                int row = t8 + 8*k2;
                gout[row*64 + col] = make_float2(a[k2].x*scale, a[k2].y*scale);
            }
        } else {
            #pragma unroll
            for (int k2 = 0; k2 < 8; ++k2) {
                int row = t8 + 8*k2;
                goutr[row*64 + col] = f2bf(scale * sqrtf(a[k2].x*a[k2].x + a[k2].y*a[k2].y));
            }
        }
    }
    __syncthreads();
}

// conv weights (256,512,3,3) fp32 -> wB[t][o][i] bf16 (i contiguous = K-contiguous B rows)
__global__ __launch_bounds__(256) void k_wconv(const float* __restrict__ w, unsigned short* __restrict__ wB) {
    int idx = blockIdx.x*256 + threadIdx.x;
    if (idx >= 9*NC*ND) return;
    int i = idx & 511;
    int rest = idx >> 9;
    int o = rest & 255;
    int t = rest >> 8;
    wB[idx] = f2bf(w[(o*NC + i)*9 + t]);
}

// proj weights (512,512) fp32 -> bf16, same [o][c] layout
__global__ __launch_bounds__(256) void k_wproj(const float* __restrict__ w, unsigned short* __restrict__ wb) {
    int i = blockIdx.x*256 + threadIdx.x;
    wb[i] = f2bf(w[i]);
}

// x (b, 4096, 512) fp32 -> spatially padded bf16 xpad[b][hp][wp][c], hp/wp in [0,70)
__global__ __launch_bounds__(256) void k_xpad(const float* __restrict__ x, unsigned short* __restrict__ xpad) {
    int idx = blockIdx.x*256 + threadIdx.x;
    int c8 = idx & 63;
    int rest = idx >> 6;
    int wp = rest % HPAD;
    int rest2 = rest / HPAD;
    int hp = rest2 % HPAD;
    int b = rest2 / HPAD;
    int h = hp - 3, w = wp - 3;
    bf16x8 v = {0,0,0,0,0,0,0,0};
    if (((unsigned)h) < 64u && ((unsigned)w) < 64u) {
        const float* s = x + (((size_t)b*NP + h*64 + w)*NC + c8*8);
        float4 f0 = *(const float4*)(s);
        float4 f1 = *(const float4*)(s + 4);
        v[0]=(short)f2bf(f0.x); v[1]=(short)f2bf(f0.y); v[2]=(short)f2bf(f0.z); v[3]=(short)f2bf(f0.w);
        v[4]=(short)f2bf(f1.x); v[5]=(short)f2bf(f1.y); v[6]=(short)f2bf(f1.z); v[7]=(short)f2bf(f1.w);
    }
    *(bf16x8*)(xpad + ((size_t)(b*HPAD*HPAD) + hp*HPAD + wp)*NC + c8*8) = v;
}

// bf16 MFMA implicit-GEMM dilated conv (d=3,pad=3) + bias + BN + ReLU -> out[b][o][p] fp32
__global__ __launch_bounds__(256, 2) void k_conv_mfma(
        const unsigned short* __restrict__ xpad, const unsigned short* __restrict__ wB,
        const float* __restrict__ cbias, const float* __restrict__ bg, const float* __restrict__ bb,
        const float* __restrict__ bm, const float* __restrict__ bv, float* __restrict__ out)
{
    __shared__ short Als[128*32];
    __shared__ short Bls[128*32];
    int tid = threadIdx.x;
    int p0 = blockIdx.x * 128;
    int o0 = blockIdx.y * 128;
    int b  = blockIdx.z;
    int lane = tid & 63;
    int wv = tid >> 6;
    int wr = wv >> 1, wc = wv & 1;
    int ln = lane & 15, kq = lane >> 4;

    f32x4 acc[4][4];
    #pragma unroll
    for (int i = 0; i < 4; ++i)
        #pragma unroll
        for (int j = 0; j < 4; ++j)
            acc[i][j] = (f32x4){0.f, 0.f, 0.f, 0.f};

    int r0 = tid >> 2;
    int c16 = tid & 3;
    int pA0 = p0 + r0, pA1 = p0 + 64 + r0;
    int h0 = pA0 >> 6, w0c = pA0 & 63;
    int h1 = pA1 >> 6, w1c = pA1 & 63;
    const unsigned short* xb = xpad + (size_t)b*(HPAD*HPAD)*NC;
    int oB0 = o0 + r0, oB1 = o0 + 64 + r0;
    short* AlsD0 = Als + tid*8;
    short* AlsD1 = Als + (256 + tid)*8;
    short* BlsD0 = Bls + tid*8;
    short* BlsD1 = Bls + (256 + tid)*8;

    for (int t = 0; t < 9; ++t) {
        int dh = (t/3)*3, dw = (t%3)*3;
        const unsigned short* ga0 = xb + ((size_t)((h0 + dh)*HPAD + (w0c + dw)))*NC + c16*8;
        const unsigned short* ga1 = xb + ((size_t)((h1 + dh)*HPAD + (w1c + dw)))*NC + c16*8;
        const unsigned short* gb0 = wB + ((size_t)(t*ND + oB0))*NC + c16*8;
        const unsigned short* gb1 = wB + ((size_t)(t*ND + oB1))*NC + c16*8;
        for (int kc = 0; kc < NC; kc += 32) {
            __syncthreads();
            load_lds16(ga0 + kc, AlsD0);
            load_lds16(ga1 + kc, AlsD1);
            load_lds16(gb0 + kc, BlsD0);
            load_lds16(gb1 + kc, BlsD1);
            __syncthreads();
            bf16x8 af[4], bfr[4];
            #pragma unroll
            for (int mi = 0; mi < 4; ++mi)
                af[mi] = *(const bf16x8*)&Als[(wr*64 + mi*16 + ln)*32 + kq*8];
            #pragma unroll
            for (int ni = 0; ni < 4; ++ni)
                bfr[ni] = *(const bf16x8*)&Bls[(wc*64 + ni*16 + ln)*32 + kq*8];
            #pragma unroll
            for (int mi = 0; mi < 4; ++mi)
                #pragma unroll
                for (int ni = 0; ni < 4; ++ni)
                    acc[mi][ni] = __builtin_amdgcn_mfma_f32_16x16x32_bf16(af[mi], bfr[ni], acc[mi][ni], 0, 0, 0);
        }
    }

    #pragma unroll
    for (int ni = 0; ni < 4; ++ni) {
        int o = o0 + wc*64 + ni*16 + ln;
        float inv = bg[o] * rsqrtf(bv[o] + 1e-5f);
        float beta = bb[o] - bm[o]*inv;
        float cbo = cbias[o];
        #pragma unroll
        for (int mi = 0; mi < 4; ++mi) {
            int p = p0 + wr*64 + mi*16 + kq*4;
            f32x4 v = acc[mi][ni];
            float4 rv;
            rv.x = fmaxf((v[0] + cbo)*inv + beta, 0.f);
            rv.y = fmaxf((v[1] + cbo)*inv + beta, 0.f);
            rv.z = fmaxf((v[2] + cbo)*inv + beta, 0.f);
            rv.w = fmaxf((v[3] + cbo)*inv + beta, 0.f);
            *(float4*)(out + ((size_t)(b*ND + o))*NP + p) = rv;
        }
    }
}

// fft2 (forward) of one 64x64 real image -> complex F[kh*64+kw]
__global__ __launch_bounds__(256) void k_fft2_fwd(const float* __restrict__ src, float2* __restrict__ F) {
    __shared__ float Re[64*FPITCH];
    __shared__ float Im[64*FPITCH];
    __shared__ float twc[64], tws[64];
    int tid = threadIdx.x;
    size_t img = blockIdx.x;
    const float* s = src + img*4096;
    if (tid < 64) { float sv, cv; __sincosf(TWO_PI*(float)tid/64.f, &sv, &cv); twc[tid]=cv; tws[tid]=sv; }
    for (int i = tid; i < 4096; i += 256) {
        Re[(i>>6)*FPITCH + (i&63)] = s[i];
        Im[(i>>6)*FPITCH + (i&63)] = 0.f;
    }
    fft64_rows<-1,0>(Re, Im, twc, tws, tid, nullptr, 1.f);
    fft64_cols<-1,2>(Re, Im, twc, tws, tid, F + img*4096, nullptr, 1.f);
}

// 4096-pt inverse FFT of one f-row (Cooley-Tukey 64x64): Z[k1+64*k2], includes 1/4096
__global__ __launch_bounds__(256) void k_ifft_row4096(const float2* __restrict__ f, float2* __restrict__ Z) {
    __shared__ float Re[64*FPITCH];
    __shared__ float Im[64*FPITCH];
    __shared__ float twc[64], tws[64];
    int tid = threadIdx.x;
    size_t img = blockIdx.x;
    const float2* s = f + img*4096;
    if (tid < 64) { float sv, cv; __sincosf(TWO_PI*(float)tid/64.f, &sv, &cv); twc[tid]=cv; tws[tid]=sv; }
    for (int i = tid; i < 4096; i += 256) {
        float2 v = s[i];
        Re[(i>>6)*FPITCH + (i&63)] = v.x;
        Im[(i>>6)*FPITCH + (i&63)] = v.y;
    }
    fft64_cols<1,1>(Re, Im, twc, tws, tid, nullptr, nullptr, 1.f);
    fft64_rows<1,1>(Re, Im, twc, tws, tid, Z + img*4096, 1.f/4096.f);
}

// ifft2 of one 64x64 complex image, abs, * 1/4096 -> bf16 [c][p]
__global__ __launch_bounds__(256) void k_ifft2_abs(const float2* __restrict__ gf, unsigned short* __restrict__ out) {
    __shared__ float Re[64*FPITCH];
    __shared__ float Im[64*FPITCH];
    __shared__ float twc[64], tws[64];
    int tid = threadIdx.x;
    size_t img = blockIdx.x;
    const float2* s = gf + img*4096;
    if (tid < 64) { float sv, cv; __sincosf(TWO_PI*(float)tid/64.f, &sv, &cv); twc[tid]=cv; tws[tid]=sv; }
    for (int i = tid; i < 4096; i += 256) {
        float2 v = s[i];
        Re[(i>>6)*FPITCH + (i&63)] = v.x;
        Im[(i>>6)*FPITCH + (i&63)] = v.y;
    }
    fft64_rows<1,0>(Re, Im, twc, tws, tid, nullptr, 1.f);
    fft64_cols<1,3>(Re, Im, twc, tws, tid, nullptr, out + img*4096, 1.f/4096.f);
}

// per-(b,ch) L2 norm of f row
__global__ __launch_bounds__(256) void k_norm(const float2* __restrict__ f, float* __restrict__ nrm) {
    size_t img = blockIdx.x;
    int tid = threadIdx.x;
    const float2* s = f + img*4096;
    float acc = 0.f;
    for (int i = tid; i < 4096; i += 256) { float2 v = s[i]; acc += v.x*v.x + v.y*v.y; }
    #pragma unroll
    for (int off = 32; off > 0; off >>= 1) acc += __shfl_down(acc, off, 64);
    __shared__ float part[4];
    if ((tid & 63) == 0) part[tid >> 6] = acc;
    __syncthreads();
    if (tid == 0) nrm[img] = fmaxf(sqrtf(part[0]+part[1]+part[2]+part[3]), 1e-12f);
}

// G[c][d] = sum_n f_c[n]*f_d[n] (complex, no conj), split over n into 8 partials
__global__ __launch_bounds__(256) void k_gram(const float2* __restrict__ f, float2* __restrict__ Gpart) {
    int split = blockIdx.x;
    int bh = blockIdx.y;
    int b = bh >> 3, h = bh & 7;
    int tid = threadIdx.x;
    int ci = tid >> 3, dg = tid & 7;
    __shared__ float2 ft[32][65];
    const float2* fb = f + ((size_t)(b*ND + h*32))*NP;
    float2 acc[4];
    acc[0]=acc[1]=acc[2]=acc[3]=make_float2(0.f,0.f);
    for (int chunk = 0; chunk < 8; ++chunk) {
        int nbase = split*512 + chunk*64;
        __syncthreads();
        for (int i = tid; i < 2048; i += 256)
            ft[i>>6][i&63] = fb[(size_t)(i>>6)*NP + nbase + (i&63)];
        __syncthreads();
        for (int nn = 0; nn < 64; ++nn) {
            float2 fc = ft[ci][nn];
            #pragma unroll
            for (int j = 0; j < 4; ++j) {
                float2 fd = ft[dg*4+j][nn];
                acc[j].x += fc.x*fd.x - fc.y*fd.y;
                acc[j].y += fc.x*fd.y + fc.y*fd.x;
            }
        }
    }
    float2* g = Gpart + ((size_t)bh*8 + split)*1024;
    #pragma unroll
    for (int j = 0; j < 4; ++j) g[ci*32 + dg*4 + j] = acc[j];
}

// reduce partials, normalize, *temp, dual softmax, then A' = (1/32) W32+ @ S
__global__ __launch_bounds__(256) void k_attn(const float2* __restrict__ Gpart, const float* __restrict__ nrm,
                                              const float* __restrict__ temp, float2* __restrict__ Ap) {
    int bh = blockIdx.x;
    int b = bh >> 3, h = bh & 7;
    int tid = threadIdx.x;
    __shared__ float2 Sm[32][33];
    __shared__ float twc[32], tws[32];
    if (tid < 32) { float sv, cv; __sincosf(TWO_PI*(float)tid/32.f, &sv, &cv); twc[tid]=cv; tws[tid]=sv; }
    const float* nb = nrm + b*ND + h*32;
    float tv = temp[h];
    const float2* gp = Gpart + (size_t)bh*8*1024;
    #pragma unroll
    for (int j = 0; j < 4; ++j) {
        int e = tid*4 + j;
        int c = e >> 5, d = e & 31;
        float2 s = make_float2(0.f, 0.f);
        for (int sp = 0; sp < 8; ++sp) { float2 v = gp[sp*1024 + e]; s.x += v.x; s.y += v.y; }
        float sc = tv / (nb[c]*nb[d]);
        Sm[c][d] = make_float2(s.x*sc, s.y*sc);
    }
    __syncthreads();
    if (tid < 32) {
        float mr = -1e30f, mi = -1e30f;
        for (int d = 0; d < 32; ++d) { float2 v = Sm[tid][d]; mr = fmaxf(mr, v.x); mi = fmaxf(mi, v.y); }
        float sr = 0.f, si = 0.f;
        for (int d = 0; d < 32; ++d) {
            float2 v = Sm[tid][d];
            v.x = __expf(v.x - mr); v.y = __expf(v.y - mi);
            sr += v.x; si += v.y;
            Sm[tid][d] = v;
        }
        float ir = 1.f/sr, ii = 1.f/si;
        for (int d = 0; d < 32; ++d) { float2 v = Sm[tid][d]; Sm[tid][d] = make_float2(v.x*ir, v.y*ii); }
    }
    __syncthreads();
    float2* ap = Ap + (size_t)bh*1024;
    #pragma unroll
    for (int j = 0; j < 4; ++j) {
        int e = tid*4 + j;
        int k = e >> 5, d = e & 31;
        float2 acc = make_float2(0.f, 0.f);
        for (int c = 0; c < 32; ++c) {
            int m = (c*k) & 31;
            float2 w = make_float2(twc[m], tws[m]);
            float2 v = Sm[c][d];
            acc.x += w.x*v.x - w.y*v.y;
            acc.y += w.x*v.y + w.y*v.x;
        }
        ap[e] = make_float2(acc.x*(1.f/32.f), acc.y*(1.f/32.f));
    }
}

// out_f2 = | A' @ Z |  per (b,head) -> bf16 [c][p]
__global__ __launch_bounds__(256) void k_outf2(const float2* __restrict__ Ap, const float2* __restrict__ Z,
                                               unsigned short* __restrict__ outf2) {
    int nc = blockIdx.x, bh = blockIdx.y;
    int b = bh >> 3, h = bh & 7;
    int tid = threadIdx.x;
    __shared__ float2 A[32][32];
    const float2* ap = Ap + (size_t)bh*1024;
    for (int i = tid; i < 1024; i += 256) A[i>>5][i&31] = ap[i];
    __syncthreads();
    int n = nc*256 + tid;
    const float2* zb = Z + ((size_t)(b*ND + h*32))*NP + n;
    float2 z[32];
    #pragma unroll
    for (int d = 0; d < 32; ++d) z[d] = zb[(size_t)d*NP];
    unsigned short* ob = outf2 + ((size_t)(b*ND + h*32))*NP + n;
    for (int k = 0; k < 32; ++k) {
        float2 acc = make_float2(0.f, 0.f);
        #pragma unroll
        for (int d = 0; d < 32; ++d) {
            float2 a = A[k][d], zz = z[d];
            acc.x += a.x*zz.x - a.y*zz.y;
            acc.y += a.x*zz.y + a.y*zz.x;
        }
        ob[(size_t)k*NP] = f2bf(sqrtf(acc.x*acc.x + acc.y*acc.y));
    }
}

// g1 = relu(BN(w1 @ Re(f)))
__global__ __launch_bounds__(256) void k_g1(const float2* __restrict__ f, const float* __restrict__ w1,
        const float* __restrict__ w1b, const float* __restrict__ gg, const float* __restrict__ gb,
        const float* __restrict__ gm, const float* __restrict__ gv, float* __restrict__ g1)
{
    int pc = blockIdx.x, b = blockIdx.y;
    int tid = threadIdx.x;
    __shared__ float w1s[16*256];
    for (int i = tid; i < 4096; i += 256) w1s[i] = w1[i];
    __syncthreads();
    int p = pc*256 + tid;
    const float2* fb = f + (size_t)b*ND*NP + p;
    float acc[16];
    #pragma unroll
    for (int j = 0; j < 16; ++j) acc[j] = 0.f;
    for (int i = 0; i < 256; ++i) {
        float v = fb[(size_t)i*NP].x;
        #pragma unroll
        for (int j = 0; j < 16; ++j) acc[j] += w1s[j*256 + i] * v;
    }
    float* go = g1 + (size_t)b*16*NP + p;
    #pragma unroll
    for (int j = 0; j < 16; ++j) {
        float inv = gg[j]*rsqrtf(gv[j] + 1e-5f);
        float val = (acc[j] + w1b[j])*inv + (gb[j] - gm[j]*inv);
        go[(size_t)j*NP] = fmaxf(val, 0.f);
    }
}

// gf = sigmoid(w2 @ g1 + b2) * f
__global__ __launch_bounds__(256) void k_gate(const float2* __restrict__ f, const float* __restrict__ g1,
        const float* __restrict__ w2, const float* __restrict__ w2b, float2* __restrict__ gf)
{
    int pc = blockIdx.x, ch = blockIdx.y, b = blockIdx.z;
    int tid = threadIdx.x;
    int p = pc*256 + tid;
    const float* g1b = g1 + (size_t)b*16*NP + p;
    float acc = w2b[ch];
    #pragma unroll
    for (int j = 0; j < 16; ++j) acc += w2[ch*16 + j] * g1b[(size_t)j*NP];
    float gate = 1.f / (1.f + __expf(-acc));
    size_t idx = ((size_t)(b*ND + ch))*NP + p;
    float2 v = f[idx];
    gf[idx] = make_float2(gate*v.x, gate*v.y);
}

// A[b][p][c] bf16 = cat(outf2b,outl2b)[c][p] + x[b][p][c]
__global__ __launch_bounds__(256) void k_prep(const unsigned short* __restrict__ outf2b,
        const unsigned short* __restrict__ outl2b, const float* __restrict__ x,
        unsigned short* __restrict__ A)
{
    int tid = threadIdx.x;
    int p = blockIdx.x*64 + (tid >> 2);
    int cs = blockIdx.y*64 + (tid & 3)*16;
    int b  = blockIdx.z;
    const unsigned short* src = (cs < ND) ? (outf2b + ((size_t)(b*ND) + cs)*NP + p)
                                          : (outl2b + ((size_t)(b*ND) + (cs - ND))*NP + p);
    float av[16];
    #pragma unroll
    for (int j = 0; j < 16; ++j) av[j] = bf2f(src[(size_t)j*NP]);
    const float* xp = x + ((size_t)(b*NP) + p)*NC + cs;
    #pragma unroll
    for (int j = 0; j < 4; ++j) {
        float4 xv = *(const float4*)(xp + j*4);
        av[j*4+0] += xv.x; av[j*4+1] += xv.y; av[j*4+2] += xv.z; av[j*4+3] += xv.w;
    }
    bf16x8 v0, v1;
    #pragma unroll
    for (int j = 0; j < 8; ++j) { v0[j] = (short)f2bf(av[j]); v1[j] = (short)f2bf(av[8+j]); }
    unsigned short* ap = A + ((size_t)(b*NP) + p)*NC + cs;
    *(bf16x8*)(ap) = v0;
    *(bf16x8*)(ap + 8) = v1;
}

// bf16 MFMA proj GEMM: out[b][p][o] = A[b][p][:] . pw[o][:] + pb[o]
__global__ __launch_bounds__(256, 2) void k_projm(
        const unsigned short* __restrict__ A, const unsigned short* __restrict__ Bw,
        const float* __restrict__ pb, float* __restrict__ out)
{
    __shared__ short Als[128*32];
    __shared__ short Bls[128*32];
    int tid = threadIdx.x;
    int p0 = blockIdx.x * 128;
    int o0 = blockIdx.y * 128;
    int b  = blockIdx.z;
    int lane = tid & 63;
    int wv = tid >> 6;
    int wr = wv >> 1, wc = wv & 1;
    int ln = lane & 15, kq = lane >> 4;

    f32x4 acc[4][4];
    #pragma unroll
    for (int i = 0; i < 4; ++i)
        #pragma unroll
        for (int j = 0; j < 4; ++j)
            acc[i][j] = (f32x4){0.f, 0.f, 0.f, 0.f};

    int r0 = tid >> 2;
    int c16 = tid & 3;
    const unsigned short* ga0 = A + ((size_t)(b*NP) + p0 + r0)*NC + c16*8;
    const unsigned short* ga1 = A + ((size_t)(b*NP) + p0 + 64 + r0)*NC + c16*8;
    const unsigned short* gb0 = Bw + (size_t)(o0 + r0)*NC + c16*8;
    const unsigned short* gb1 = Bw + (size_t)(o0 + 64 + r0)*NC + c16*8;
    short* AlsD0 = Als + tid*8;
    short* AlsD1 = Als + (256 + tid)*8;
    short* BlsD0 = Bls + tid*8;
    short* BlsD1 = Bls + (256 + tid)*8;

    for (int kc = 0; kc < NC; kc += 32) {
        __syncthreads();
        load_lds16(ga0 + kc, AlsD0);
        load_lds16(ga1 + kc, AlsD1);
        load_lds16(gb0 + kc, BlsD0);
        load_lds16(gb1 + kc, BlsD1);
        __syncthreads();
        bf16x8 af[4], bfr[4];
        #pragma unroll
        for (int mi = 0; mi < 4; ++mi)
            af[mi] = *(const bf16x8*)&Als[(wr*64 + mi*16 + ln)*32 + kq*8];
        #pragma unroll
        for (int ni = 0; ni < 4; ++ni)
            bfr[ni] = *(const bf16x8*)&Bls[(wc*64 + ni*16 + ln)*32 + kq*8];
        #pragma unroll
        for (int mi = 0; mi < 4; ++mi)
            #pragma unroll
            for (int ni = 0; ni < 4; ++ni)
                acc[mi][ni] = __builtin_amdgcn_mfma_f32_16x16x32_bf16(af[mi], bfr[ni], acc[mi][ni], 0, 0, 0);
    }

    // C/D: col(ln)=o, row(kq*4+reg)=p. 16 lanes x 4B consecutive in o => full 64B lines.
    #pragma unroll
    for (int ni = 0; ni < 4; ++ni) {
        int o = o0 + wc*64 + ni*16 + ln;
        float bias = pb[o];
        #pragma unroll
        for (int mi = 0; mi < 4; ++mi) {
            int p = p0 + wr*64 + mi*16 + kq*4;
            f32x4 v = acc[mi][ni];
            float* op = out + ((size_t)(b*NP) + p)*NC + o;
            op[0]        = v[0] + bias;
            op[NC]       = v[1] + bias;
            op[2*NC]     = v[2] + bias;
            op[3*(size_t)NC] = v[3] + bias;
        }
    }
}

extern "C" void kernel_launch(void* const* d_in, const int* in_sizes, int n_in,
                              void* d_out, int out_size, void* d_ws, size_t ws_size,
                              hipStream_t stream)
{
    const float* x      = (const float*)d_in[0];
    const float* conv_w = (const float*)d_in[1];
    const float* conv_b = (const float*)d_in[2];
    const float* bn2g   = (const float*)d_in[3];
    const float* bn2b   = (const float*)d_in[4];
    const float* bn2m   = (const float*)d_in[5];
    const float* bn2v   = (const float*)d_in[6];
    const float* temp   = (const float*)d_in[7];
    const float* w1w    = (const float*)d_in[8];
    const float* w1b    = (const float*)d_in[9];
    const float* bnwg   = (const float*)d_in[10];
    const float* bnwb   = (const float*)d_in[11];
    const float* bnwm   = (const float*)d_in[12];
    const float* bnwv   = (const float*)d_in[13];
    const float* w2w    = (const float*)d_in[14];
    const float* w2b    = (const float*)d_in[15];
    const float* projw  = (const float*)d_in[16];
    const float* projb  = (const float*)d_in[17];
    float* out = (float*)d_out;

    char* ws = (char*)d_ws;
    // Head overlay region [0, 6,823,936):
    //   wB bf16 (2,359,296 B) during conv; nrm/Gpart/Ap/g1 reuse it afterwards.
    unsigned short* wB = (unsigned short*)(ws);
    float*  nrm   = (float*)(ws);
    float2* Gpart = (float2*)(ws + 8192);
    float2* Ap    = (float2*)(ws + 8192 + 4194304);
    float*  g1    = (float*)(ws + 8192 + 4194304 + 524288);
    char* base = ws + 6823936;
    // conv region [base, +33.5MB): conv fp32 (dead after fft2_fwd), then outf2b bf16 (16.7MB)
    float*  conv  = (float*)(base);
    unsigned short* outf2b = (unsigned short*)(base);
    // f region [base+33.5MB, +67MB): xpad bf16 overlay before fft2_fwd; f complex;
    //   after k_gate f is dead -> outl2b bf16 (16.7MB) at its base
    float2* f     = (float2*)(base + 33554432);
    unsigned short* xpad = (unsigned short*)(base + 33554432);
    unsigned short* outl2b = (unsigned short*)(base + 33554432);
    // Z region [base+100.6MB, +67MB): Z complex, then gf overlay; after ifft2_abs dead ->
    //   pwb bf16 (0.5MB) at base, Abf bf16 (33.5MB) at +4MB
    char* zbase = base + 33554432 + 67108864;
    float2* Z     = (float2*)(zbase);
    float2* gf    = (float2*)(zbase);
    unsigned short* pwb = (unsigned short*)(zbase);
    unsigned short* Abf = (unsigned short*)(zbase + 4194304);
    // total workspace used: 174,596,096 bytes

    k_wconv<<<dim3(4608), 256, 0, stream>>>(conv_w, wB);
    k_xpad<<<dim3(9800), 256, 0, stream>>>(x, xpad);
    k_conv_mfma<<<dim3(32, 2, 8), 256, 0, stream>>>(xpad, wB, conv_b, bn2g, bn2b, bn2m, bn2v, conv);
    k_fft2_fwd<<<dim3(2048), 256, 0, stream>>>(conv, f);
    k_norm<<<dim3(2048), 256, 0, stream>>>(f, nrm);
    k_gram<<<dim3(8, 64), 256, 0, stream>>>(f, Gpart);
    k_attn<<<dim3(64), 256, 0, stream>>>(Gpart, nrm, temp, Ap);
    k_ifft_row4096<<<dim3(2048), 256, 0, stream>>>(f, Z);
    k_outf2<<<dim3(16, 64), 256, 0, stream>>>(Ap, Z, outf2b);
    k_g1<<<dim3(16, 8), 256, 0, stream>>>(f, w1w, w1b, bnwg, bnwb, bnwm, bnwv, g1);
    k_gate<<<dim3(16, 256, 8), 256, 0, stream>>>(f, g1, w2w, w2b, gf);
    k_ifft2_abs<<<dim3(2048), 256, 0, stream>>>(gf, outl2b);
    k_wproj<<<dim3(1024), 256, 0, stream>>>(projw, pwb);
    k_prep<<<dim3(64, 8, 8), 256, 0, stream>>>(outf2b, outl2b, x, Abf);
    k_projm<<<dim3(32, 4, 8), 256, 0, stream>>>(Abf, pwb, projb, out);
}